// Round 13
// baseline (302.819 us; speedup 1.0000x reference)
//
#include <hip/hip_runtime.h>
#include <hip/hip_bf16.h>
#include <math.h>

#define TSTEPS 128
#define HD 16      // GRU hidden
#define G3 48      // 3*H gates
#define AD 32      // 2*H attention dim
#define CHUNK 8    // serial steps per gx-MFMA chunk
#define NCHK 16
#define RROW 18    // ring row halfs (16 + 2 pad -> conflict-free group reads)
#define RING_PW (4 * 3 * CHUNK * RROW)   // 1728 halfs per wave
#define SROW (TSTEPS * HD + 8)           // fallback: halfs per seq-dir history

#define SC1 1.44269504088896340736f   // log2(e)   : sigmoid prescale
#define SC2 2.88539008177792681472f   // 2*log2(e) : tanh prescale

typedef _Float16 h2 __attribute__((ext_vector_type(2)));
typedef _Float16 f16x8 __attribute__((ext_vector_type(8)));
typedef float f32x4 __attribute__((ext_vector_type(4)));

#if defined(__has_builtin)
#  if __has_builtin(__builtin_amdgcn_exp2f)
#    define EXP2F(x) __builtin_amdgcn_exp2f(x)
#  endif
#  if __has_builtin(__builtin_amdgcn_rcpf)
#    define RCPF(x) __builtin_amdgcn_rcpf(x)
#  endif
#endif
#ifndef EXP2F
#  define EXP2F(x) exp2f(x)
#endif
#ifndef RCPF
#  define RCPF(x) (1.0f / (x))
#endif

__device__ __forceinline__ float fdot2(h2 a, h2 b, float c) {
    return __builtin_amdgcn_fdot2(a, b, c, false);
}
// tanh(x) with pre-scaled input u = 2*log2e*x
__device__ __forceinline__ float tanh_pre(float u) {
    return 1.0f - 2.0f * RCPF(EXP2F(u) + 1.0f);
}

// Guarded row-major MFMA fragment load (k = k0+e, 0 beyond D), scaled.
template<int D>
__device__ __forceinline__ f16x8 load_frag(const float* __restrict__ rowptr,
                                           int k0, float scale) {
    f16x8 f;
    #pragma unroll
    for (int e = 0; e < 8; ++e) {
        const int k = k0 + e;
        f[e] = (k < D) ? (_Float16)(rowptr[k] * scale) : (_Float16)0.0f;
    }
    return f;
}

// One block = 128 threads = 2 waves = FOUR sequences. wave0 = forward dir,
// wave1 = backward dir (each wave holds ONE dir's weights -> fewer VGPRs).
// Lane (g,u): seq g (0..3) of this block, h-unit u; computes all three gates
// (24 fdot2 + 3 exp2 + 3 rcp) -- no cross-lane ops in the serial chain.
// gx = x @ Wih^T on the matrix pipe per 8-step chunk into a per-wave LDS ring
// (same-wave DS ordering -> barrier-free).
// GH=true: h history packed per-chunk to GLOBAL (d_ws, L2-hot), serial
// exchange in a 256B LDS row -> ~7KB LDS. GH=false: in-LDS history fallback.
template<int D, bool HAS_PROJ, bool GH>
__global__ __launch_bounds__(128, 2)
void gru_attn_kernel(
    const float* __restrict__ x,                      // [S, TSTEPS, D]
    const float* __restrict__ Wih_f, const float* __restrict__ Whh_f,
    const float* __restrict__ bih_f, const float* __restrict__ bhh_f,
    const float* __restrict__ Wih_b, const float* __restrict__ Whh_b,
    const float* __restrict__ bih_b, const float* __restrict__ bhh_b,
    const float* __restrict__ Wa, const float* __restrict__ ba,
    const float* __restrict__ ctxv,
    const float* __restrict__ Wm, const float* __restrict__ bm,
    _Float16* __restrict__ ghist,                     // [sd][chunk][u][8] (GH)
    float* __restrict__ out, int out_cols)
{
    __shared__ __align__(16) _Float16 ring[2 * RING_PW];          // 6912 B (+attn overlay)
    __shared__ __align__(16) _Float16 h1pool[GH ? 128 : 8 * SROW];

    const int tid  = threadIdx.x;
    const int lane = tid & 63;
    const int wv   = tid >> 6;
    const int dir  = wv;                 // wave0 = fwd, wave1 = bwd
    const int g    = lane >> 4;          // seq index within block (0..3)
    const int u    = lane & 15;          // h-unit / fragment row/col
    const int k0   = g * 8;              // fragment k base (same lanes as g)
    const int sd   = wv * 4 + g;         // (dir,seq) row id in block (0..7)

    // ---- per-lane recurrent weights (prescaled) + biases ----
    const float* WihP = dir ? Wih_b : Wih_f;
    const float* WhhP = dir ? Whh_b : Whh_f;
    const float* bihP = dir ? bih_b : bih_f;
    const float* bhhP = dir ? bhh_b : bhh_f;

    h2 wr_[8], wz_[8], wn_[8];
    {
        const float4* wrp = (const float4*)(WhhP + u * HD);
        const float4* wzp = (const float4*)(WhhP + (HD + u) * HD);
        const float4* wnp = (const float4*)(WhhP + (2 * HD + u) * HD);
        #pragma unroll
        for (int p = 0; p < 4; ++p) {
            const float4 a = wrp[p], b = wzp[p], cn = wnp[p];
            wr_[2*p]   = (h2){(_Float16)(a.x * SC1), (_Float16)(a.y * SC1)};
            wr_[2*p+1] = (h2){(_Float16)(a.z * SC1), (_Float16)(a.w * SC1)};
            wz_[2*p]   = (h2){(_Float16)(b.x * SC1), (_Float16)(b.y * SC1)};
            wz_[2*p+1] = (h2){(_Float16)(b.z * SC1), (_Float16)(b.w * SC1)};
            wn_[2*p]   = (h2){(_Float16)(cn.x * SC2), (_Float16)(cn.y * SC2)};
            wn_[2*p+1] = (h2){(_Float16)(cn.z * SC2), (_Float16)(cn.w * SC2)};
        }
    }
    const float brz = (bihP[u] + bhhP[u]) * SC1;
    const float bzz = (bihP[HD + u] + bhhP[HD + u]) * SC1;
    const float bxn = bihP[2 * HD + u] * SC2;
    const float bhn = bhhP[2 * HD + u] * SC2;

    // ---- persistent B fragments: this wave's dir only ----
    f16x8 bfrag[3];
    #pragma unroll
    for (int n = 0; n < 3; ++n)
        bfrag[n] = load_frag<D>(WihP + (16 * n + u) * D, k0, n < 2 ? SC1 : SC2);

    // A-fragment sources: tile A = seqs {0,1}, tile B = seqs {2,3}
    const size_t xstride = (size_t)TSTEPS * D;
    const float* xA0 = x + (size_t)(blockIdx.x * 4 + (u >> 3)) * xstride;
    const float* xB0 = xA0 + 2 * xstride;
    const int lsA = u & 7;

    _Float16* ringw = ring + wv * RING_PW;
    const _Float16* ringrd = ringw + (g * 3 * CHUNK) * RROW + u;
    // MFMA C rows: lsb0..lsb0+3 stay within one seq half
    const int lsb0  = ((lane >> 4) & 3) * 4;
    const int wseqA = lsb0 >> 3;          // 0 or 1
    const int wseqB = 2 + wseqA;
    const int wlsb  = lsb0 & 7;           // 0 or 4

    // history pointers
    _Float16* gh_lane = nullptr;
    _Float16* h1w = nullptr;
    const _Float16* h1r = nullptr;
    if (GH) {
        const size_t sdG = (size_t)blockIdx.x * 8 + sd;
        gh_lane = ghist + (sdG * NCHK * HD + u) * 8;   // + c*HD*8 per chunk
        h1w = h1pool + sd * HD + u;                    // exchange row
        h1r = h1pool + sd * HD;
    } else {
        h1w = h1pool + sd * SROW + u;
        h1r = h1pool + sd * SROW;
    }

    float h_own = 0.0f;

    // t mapping: fwd t=s, bwd t=127-s
    f16x8 afA = load_frag<D>(xA0 + (size_t)(dir ? (TSTEPS - 1 - lsA) : lsA) * D, k0, 1.0f);
    f16x8 afB = load_frag<D>(xB0 + (size_t)(dir ? (TSTEPS - 1 - lsA) : lsA) * D, k0, 1.0f);

    for (int c = 0; c < NCHK; ++c) {
        // ---- gx via MFMA -> ring ----
        #pragma unroll
        for (int n = 0; n < 3; ++n) {
            f32x4 a0 = {0.f, 0.f, 0.f, 0.f};
            a0 = __builtin_amdgcn_mfma_f32_16x16x32_f16(afA, bfrag[n], a0, 0, 0, 0);
            #pragma unroll
            for (int q = 0; q < 4; ++q)
                ringw[((wseqA * 3 + n) * CHUNK + wlsb + q) * RROW + u] = (_Float16)a0[q];
            f32x4 a1 = {0.f, 0.f, 0.f, 0.f};
            a1 = __builtin_amdgcn_mfma_f32_16x16x32_f16(afB, bfrag[n], a1, 0, 0, 0);
            #pragma unroll
            for (int q = 0; q < 4; ++q)
                ringw[((wseqB * 3 + n) * CHUNK + wlsb + q) * RROW + u] = (_Float16)a1[q];
        }
        // ---- prefetch next chunk's A fragments ----
        f16x8 afAn, afBn;
        if (c + 1 < NCHK) {
            const int s0 = (c + 1) * CHUNK + lsA;
            const size_t t0 = (size_t)(dir ? (TSTEPS - 1 - s0) : s0) * D;
            afAn = load_frag<D>(xA0 + t0, k0, 1.0f);
            afBn = load_frag<D>(xB0 + t0, k0, 1.0f);
        }

        f16x8 hpk;   // GH: packed history for this chunk

        // ---- serial 8 steps: all lanes active, 3 gates per lane, no shuffles ----
        #pragma unroll
        for (int ls = 0; ls < CHUNK; ++ls) {
            const float gxr = (float)ringrd[(0 * CHUNK + ls) * RROW];
            const float gxz = (float)ringrd[(1 * CHUNK + ls) * RROW];
            const float gxn = (float)ringrd[(2 * CHUNK + ls) * RROW] + bxn;

            float sr = brz, sr1 = 0.f, sz = bzz, sz1 = 0.f, sn = bhn, sn1 = 0.f;
            if (!(c == 0 && ls == 0)) {
                const f16x8* hp = GH
                    ? (const f16x8*)h1r
                    : (const f16x8*)(h1r + (c * CHUNK + ls - 1) * HD);
                const f16x8 hA = hp[0], hB = hp[1];
                sr  = fdot2(wr_[0], (h2){hA[0], hA[1]}, sr );
                sr1 = fdot2(wr_[1], (h2){hA[2], hA[3]}, sr1);
                sr  = fdot2(wr_[2], (h2){hA[4], hA[5]}, sr );
                sr1 = fdot2(wr_[3], (h2){hA[6], hA[7]}, sr1);
                sr  = fdot2(wr_[4], (h2){hB[0], hB[1]}, sr );
                sr1 = fdot2(wr_[5], (h2){hB[2], hB[3]}, sr1);
                sr  = fdot2(wr_[6], (h2){hB[4], hB[5]}, sr );
                sr1 = fdot2(wr_[7], (h2){hB[6], hB[7]}, sr1);
                sz  = fdot2(wz_[0], (h2){hA[0], hA[1]}, sz );
                sz1 = fdot2(wz_[1], (h2){hA[2], hA[3]}, sz1);
                sz  = fdot2(wz_[2], (h2){hA[4], hA[5]}, sz );
                sz1 = fdot2(wz_[3], (h2){hA[6], hA[7]}, sz1);
                sz  = fdot2(wz_[4], (h2){hB[0], hB[1]}, sz );
                sz1 = fdot2(wz_[5], (h2){hB[2], hB[3]}, sz1);
                sz  = fdot2(wz_[6], (h2){hB[4], hB[5]}, sz );
                sz1 = fdot2(wz_[7], (h2){hB[6], hB[7]}, sz1);
                sn  = fdot2(wn_[0], (h2){hA[0], hA[1]}, sn );
                sn1 = fdot2(wn_[1], (h2){hA[2], hA[3]}, sn1);
                sn  = fdot2(wn_[2], (h2){hA[4], hA[5]}, sn );
                sn1 = fdot2(wn_[3], (h2){hA[6], hA[7]}, sn1);
                sn  = fdot2(wn_[4], (h2){hB[0], hB[1]}, sn );
                sn1 = fdot2(wn_[5], (h2){hB[2], hB[3]}, sn1);
                sn  = fdot2(wn_[6], (h2){hB[4], hB[5]}, sn );
                sn1 = fdot2(wn_[7], (h2){hB[6], hB[7]}, sn1);
            }
            const float ghr = sr + sr1;
            const float ghz = sz + sz1;
            const float ghn = sn + sn1;

            const float r  = RCPF(1.0f + EXP2F(-(gxr + ghr)));
            const float zz = RCPF(1.0f + EXP2F(-(gxz + ghz)));
            const float nv = tanh_pre(gxn + r * ghn);
            const float hnew = nv + zz * (h_own - nv);
            h_own = hnew;
            const _Float16 hh16 = (_Float16)hnew;
            if (GH) {
                h1w[0] = hh16;
                hpk[ls] = hh16;
            } else {
                h1w[(c * CHUNK + ls) * HD] = hh16;
            }
        }
        if (GH) {
            *reinterpret_cast<f16x8*>(gh_lane + c * HD * 8) = hpk;   // 4x256B/wave
        }
        afA = afAn;
        afB = afBn;
    }
    __syncthreads();   // drains vmcnt+lgkmcnt: history visible to attention

    // attention scratch overlays the (now dead) ring
    float* w_sh = reinterpret_cast<float*>(ring);          // 128 floats
    float* red  = reinterpret_cast<float*>(ring) + 128;    // 4 floats
    float* cvp  = reinterpret_cast<float*>(ring) + 136;    // 128 floats

    // ---- Attention per sequence (4 per block) ----
    // fwd sd = S (wave0), bwd sd = 4 + S (wave1)
    for (int S = 0; S < 4; ++S) {
        const size_t sdfG = (size_t)blockIdx.x * 8 + S;
        const size_t sdbG = sdfG + 4;
        float hh[AD];
        if (GH) {
            const int t = tid;
            const int s = TSTEPS - 1 - t;      // bwd storage index for this t
            #pragma unroll
            for (int i = 0; i < HD; ++i) {
                hh[i]      = (float)ghist[((sdfG * NCHK + (t >> 3)) * HD + i) * 8 + (t & 7)];
                hh[HD + i] = (float)ghist[((sdbG * NCHK + (s >> 3)) * HD + i) * 8 + (s & 7)];
            }
        } else {
            const int sdf = S, sdb = 4 + S;
            const f16x8* fp = (const f16x8*)(h1pool + sdf * SROW + tid * HD);
            const f16x8* bp = (const f16x8*)(h1pool + sdb * SROW + (TSTEPS - 1 - tid) * HD);
            const f16x8 f0 = fp[0], f1 = fp[1], b0v = bp[0], b1v = bp[1];
            #pragma unroll
            for (int e = 0; e < 8; ++e) {
                hh[e]      = (float)f0[e];
                hh[8 + e]  = (float)f1[e];
                hh[16 + e] = (float)b0v[e];
                hh[24 + e] = (float)b1v[e];
            }
        }
        float st = 0.0f;
        for (int i = 0; i < AD; ++i) {
            float a0 = ba[i], a1 = 0.f;
            const float* war = &Wa[i * AD];
            #pragma unroll
            for (int k = 0; k < AD; k += 2) {
                a0 += war[k] * hh[k];
                a1 += war[k + 1] * hh[k + 1];
            }
            st += tanh_pre(SC2 * (a0 + a1)) * ctxv[i];
        }
        // softmax over the 128 t's (2 waves)
        float mx = st;
        #pragma unroll
        for (int off = 32; off > 0; off >>= 1) mx = fmaxf(mx, __shfl_xor(mx, off));
        if (lane == 0) red[wv] = mx;
        __syncthreads();
        mx = fmaxf(red[0], red[1]);
        const float e = EXP2F(SC1 * (st - mx));
        float ss = e;
        #pragma unroll
        for (int off = 32; off > 0; off >>= 1) ss += __shfl_xor(ss, off);
        if (lane == 0) red[2 + wv] = ss;
        __syncthreads();
        const float Z = red[2] + red[3];
        w_sh[tid] = e * RCPF(Z);
        __syncthreads();

        // partial cv: 4 groups of 32 t's
        {
            const int g4 = tid >> 5, i4 = tid & 31;
            float acc = 0.0f;
            for (int k = 0; k < 32; ++k) {
                const int tt = g4 * 32 + k;
                float hv;
                if (GH) {
                    if (i4 < HD) {
                        hv = (float)ghist[((sdfG * NCHK + (tt >> 3)) * HD + i4) * 8 + (tt & 7)];
                    } else {
                        const int sb = TSTEPS - 1 - tt;
                        hv = (float)ghist[((sdbG * NCHK + (sb >> 3)) * HD + (i4 - HD)) * 8 + (sb & 7)];
                    }
                } else {
                    hv = (i4 < HD)
                        ? (float)h1pool[S * SROW + tt * HD + i4]
                        : (float)h1pool[(4 + S) * SROW + (TSTEPS - 1 - tt) * HD + (i4 - HD)];
                }
                acc += w_sh[tt] * hv;
            }
            cvp[g4 * AD + i4] = acc;
        }
        __syncthreads();

        if (HAS_PROJ) {
            if (tid < HD) {
                float a = bm[tid];
                #pragma unroll
                for (int i = 0; i < AD; ++i)
                    a += Wm[tid * AD + i] *
                         (cvp[i] + cvp[AD + i] + cvp[2 * AD + i] + cvp[3 * AD + i]);
                out[(size_t)(blockIdx.x * 4 + S) * out_cols + tid] = a;
            }
        } else {
            if (tid < AD)
                out[(size_t)(blockIdx.x * 4 + S) * out_cols + tid] =
                    cvp[tid] + cvp[AD + tid] + cvp[2 * AD + tid] + cvp[3 * AD + tid];
        }
        __syncthreads();
    }
}

extern "C" void kernel_launch(void* const* d_in, const int* in_sizes, int n_in,
                              void* d_out, int out_size, void* d_ws, size_t ws_size,
                              hipStream_t stream) {
    const float* x     = (const float*)d_in[0];
    const float* Wih1f = (const float*)d_in[1];
    const float* Whh1f = (const float*)d_in[2];
    const float* bih1f = (const float*)d_in[3];
    const float* bhh1f = (const float*)d_in[4];
    const float* Wih1b = (const float*)d_in[5];
    const float* Whh1b = (const float*)d_in[6];
    const float* bih1b = (const float*)d_in[7];
    const float* bhh1b = (const float*)d_in[8];
    const float* Wih2f = (const float*)d_in[9];
    const float* Whh2f = (const float*)d_in[10];
    const float* bih2f = (const float*)d_in[11];
    const float* bhh2f = (const float*)d_in[12];
    const float* Wih2b = (const float*)d_in[13];
    const float* Whh2b = (const float*)d_in[14];
    const float* bih2b = (const float*)d_in[15];
    const float* bhh2b = (const float*)d_in[16];
    const float* Wa1   = (const float*)d_in[17];
    const float* ba1   = (const float*)d_in[18];
    const float* ctx1  = (const float*)d_in[19];
    const float* Wa2   = (const float*)d_in[20];
    const float* ba2   = (const float*)d_in[21];
    const float* ctx2  = (const float*)d_in[22];
    const float* Wm    = (const float*)d_in[23];
    const float* bm    = (const float*)d_in[24];

    float* flow = (float*)d_ws;                               // [8192,16] = 512KB
    const size_t histOff = 1u << 20;                          // 1 MB
    const size_t histBytes = (size_t)16384 * NCHK * HD * 8 * 2; // 64 MB
    _Float16* ghist = (_Float16*)((char*)d_ws + histOff);
    const bool gh = (ws_size >= histOff + histBytes);
    float* outp = (float*)d_out;                              // [64, 32]

    if (gh) {
        gru_attn_kernel<25, true, true><<<2048, 128, 0, stream>>>(
            x, Wih1f, Whh1f, bih1f, bhh1f, Wih1b, Whh1b, bih1b, bhh1b,
            Wa1, ba1, ctx1, Wm, bm, ghist, flow, 16);
        gru_attn_kernel<16, false, true><<<16, 128, 0, stream>>>(
            flow, Wih2f, Whh2f, bih2f, bhh2f, Wih2b, Whh2b, bih2b, bhh2b,
            Wa2, ba2, ctx2, nullptr, nullptr, ghist, outp, 32);
    } else {
        gru_attn_kernel<25, true, false><<<2048, 128, 0, stream>>>(
            x, Wih1f, Whh1f, bih1f, bhh1f, Wih1b, Whh1b, bih1b, bhh1b,
            Wa1, ba1, ctx1, Wm, bm, nullptr, flow, 16);
        gru_attn_kernel<16, false, false><<<16, 128, 0, stream>>>(
            flow, Wih2f, Whh2f, bih2f, bhh2f, Wih2b, Whh2b, bih2b, bhh2b,
            Wa2, ba2, ctx2, nullptr, nullptr, nullptr, outp, 32);
    }
}

// Round 14
// 234.618 us; speedup vs baseline: 1.2907x; 1.2907x over previous
//
#include <hip/hip_runtime.h>
#include <hip/hip_bf16.h>
#include <math.h>

#define TSTEPS 128
#define HD 16      // GRU hidden
#define G3 48      // 3*H gates
#define AD 32      // 2*H attention dim
#define H1ROW 16   // h1 history row: 16 halfs = 32B (16B-aligned, broadcast reads)
#define CHUNK 16   // serial steps per gx-MFMA chunk
#define NCHUNK 8
#define RW 52      // ring row width in halfs (>=48); 4 rows = 104 dw = +8 banks
#define RING_BYTES (2 * CHUNK * RW * 2)   // 3328 B, reused by attention scratch

#define SC1 1.44269504088896340736f   // log2(e)   : sigmoid prescale
#define SC2 2.88539008177792681472f   // 2*log2(e) : tanh prescale

typedef _Float16 h2 __attribute__((ext_vector_type(2)));
typedef _Float16 f16x8 __attribute__((ext_vector_type(8)));
typedef float f32x4 __attribute__((ext_vector_type(4)));
typedef unsigned int uint2v __attribute__((ext_vector_type(2)));

#if defined(__has_builtin)
#  if __has_builtin(__builtin_amdgcn_exp2f)
#    define EXP2F(x) __builtin_amdgcn_exp2f(x)
#  endif
#  if __has_builtin(__builtin_amdgcn_rcpf)
#    define RCPF(x) __builtin_amdgcn_rcpf(x)
#  endif
#  if __has_builtin(__builtin_amdgcn_permlane16_swap) && __has_builtin(__builtin_amdgcn_permlane32_swap)
#    define HAS_PLSWAP 1
#  endif
#endif
#ifndef EXP2F
#  define EXP2F(x) exp2f(x)
#endif
#ifndef RCPF
#  define RCPF(x) (1.0f / (x))
#endif

// tanh(x) with pre-scaled input u = 2*log2e*x
__device__ __forceinline__ float tanh_pre(float u) {
    return 1.0f - 2.0f * RCPF(EXP2F(u) + 1.0f);
}

// Guarded row-major MFMA fragment load (k = k0+e, 0 beyond D), scaled.
template<int D>
__device__ __forceinline__ f16x8 load_frag(const float* __restrict__ rowptr,
                                           int k0, float scale) {
    f16x8 f;
    #pragma unroll
    for (int e = 0; e < 8; ++e) {
        const int k = k0 + e;
        f[e] = (k < D) ? (_Float16)(rowptr[k] * scale) : (_Float16)0.0f;
    }
    return f;
}

// One block = one sequence. 128 threads = 2 waves (wave0 fwd, wave1 bwd).
// gx = x @ Wih^T on the matrix pipe (per-16-step chunk, per-wave LDS ring,
// barrier-free by same-wave DS ordering). Serial loop: lane j<48 owns gate j,
// gh = fdot2 over the fp16 h history row. Cross-lane gate exchange uses
// gfx950 v_permlane16/32_swap (VALU pipe) instead of ds_bpermute: DS ops
// drop 7 -> 4 per step and the crossbar latency leaves the serial chain.
template<int D, bool HAS_PROJ>
__global__ __launch_bounds__(128, 6)
void gru_attn_kernel(
    const float* __restrict__ x,                      // [S, TSTEPS, D]
    const float* __restrict__ Wih_f, const float* __restrict__ Whh_f,
    const float* __restrict__ bih_f, const float* __restrict__ bhh_f,
    const float* __restrict__ Wih_b, const float* __restrict__ Whh_b,
    const float* __restrict__ bih_b, const float* __restrict__ bhh_b,
    const float* __restrict__ Wa, const float* __restrict__ ba,
    const float* __restrict__ ctxv,
    const float* __restrict__ Wm, const float* __restrict__ bm,
    float* __restrict__ out, int out_cols)
{
    __shared__ __align__(16) unsigned char smem_u[RING_BYTES];    // ring / attn scratch
    __shared__ __align__(16) _Float16 h1pool[2][TSTEPS][H1ROW];   // 8192 B, s-indexed

    const int tid  = threadIdx.x;
    const int seq  = blockIdx.x;
    const int lane = tid & 63;
    const int wave = tid >> 6;

    // ---- Recurrence with chunked MFMA gx precompute ----
    {
        const int dirw = __builtin_amdgcn_readfirstlane(wave);   // wave-uniform
        const float* Wih = dirw ? Wih_b : Wih_f;
        const float* Whh = dirw ? Whh_b : Whh_f;
        const float* bihp = dirw ? bih_b : bih_f;
        const float* bhhp = dirw ? bhh_b : bhh_f;

        const int jc = (lane < G3) ? lane : (G3 - 1);   // clamped gate index
        const int fr = lane & 15;                       // fragment row/col
        const int k0 = ((lane >> 4) & 3) * 8;           // fragment k base
        const float scj = (jc < 2 * HD) ? SC1 : SC2;    // gate prescale

        // recurrent weights fp16 (prescaled) + biases (prescaled)
        h2 whhv[HD / 2];
        #pragma unroll
        for (int k = 0; k < HD; ++k)
            whhv[k >> 1][k & 1] = (_Float16)(Whh[jc * HD + k] * scj);
        const float gb = bihp[jc] * scj;
        const float bh = bhhp[jc] * scj;

        // persistent B fragments: Wih rows (gates), prescaled per gate block
        f16x8 bfrag[3];
        #pragma unroll
        for (int n = 0; n < 3; ++n)
            bfrag[n] = load_frag<D>(Wih + (16 * n + fr) * D, k0, n < 2 ? SC1 : SC2);

        const float* xbase = x + (size_t)seq * TSTEPS * D;
        _Float16* myring = reinterpret_cast<_Float16*>(smem_u) + wave * CHUNK * RW;
        const _Float16* ringrd = myring + jc;                    // + imm ls*RW
        _Float16* rw_ = myring + (((lane >> 4) & 3) * 4) * RW + fr;  // + imm (q*RW+16n)

        float h_own = 0.0f;          // lane k<16 holds h[k]

        // A fragment for chunk 0
        f16x8 afrag;
        {
            const int t0 = dirw ? (TSTEPS - 1 - fr) : fr;
            afrag = load_frag<D>(xbase + t0 * D, k0, 1.0f);
        }

        for (int c = 0; c < NCHUNK; ++c) {
            // gx via MFMA (matrix pipe) -> per-wave ring (bank-tiled rows)
            #pragma unroll
            for (int n = 0; n < 3; ++n) {
                f32x4 acc = {0.f, 0.f, 0.f, 0.f};
                acc = __builtin_amdgcn_mfma_f32_16x16x32_f16(afrag, bfrag[n], acc, 0, 0, 0);
                #pragma unroll
                for (int q = 0; q < 4; ++q)
                    rw_[q * RW + 16 * n] = (_Float16)acc[q];     // imm offsets
            }
            // prefetch next chunk's A fragment (hidden under 16 serial steps)
            f16x8 afrag_n;
            if (c + 1 < NCHUNK) {
                const int sA = (c + 1) * CHUNK + fr;
                const int tA = dirw ? (TSTEPS - 1 - sA) : sA;
                afrag_n = load_frag<D>(xbase + tA * D, k0, 1.0f);
            }

            // serial 16 steps, fully unrolled (imm DS offsets)
            const _Float16* hprev = &h1pool[dirw][0][0] + (c * CHUNK - 1) * H1ROW;
            _Float16* hwr = &h1pool[dirw][c * CHUNK][lane & 15];

            #pragma unroll
            for (int ls = 0; ls < CHUNK; ++ls) {
                const float gxv = gb + (float)ringrd[ls * RW];

                float ghv;
                if (ls == 0 && c == 0) {                 // only step 0 (runtime c==0)
                    ghv = bh;
                } else {
                    const f16x8 hA = *reinterpret_cast<const f16x8*>(hprev + ls * H1ROW);
                    const f16x8 hB = *reinterpret_cast<const f16x8*>(hprev + ls * H1ROW + 8);
                    float b0 = bh, b1 = 0.f;
                    b0 = __builtin_amdgcn_fdot2(whhv[0], (h2){hA[0], hA[1]}, b0, false);
                    b1 = __builtin_amdgcn_fdot2(whhv[1], (h2){hA[2], hA[3]}, b1, false);
                    b0 = __builtin_amdgcn_fdot2(whhv[2], (h2){hA[4], hA[5]}, b0, false);
                    b1 = __builtin_amdgcn_fdot2(whhv[3], (h2){hA[6], hA[7]}, b1, false);
                    b0 = __builtin_amdgcn_fdot2(whhv[4], (h2){hB[0], hB[1]}, b0, false);
                    b1 = __builtin_amdgcn_fdot2(whhv[5], (h2){hB[2], hB[3]}, b1, false);
                    b0 = __builtin_amdgcn_fdot2(whhv[6], (h2){hB[4], hB[5]}, b0, false);
                    b1 = __builtin_amdgcn_fdot2(whhv[7], (h2){hB[6], hB[7]}, b1, false);
                    ghv = b0 + b1;
                }

                // lanes 0..15: r | 16..31: z | 32..47: n   (inputs pre-scaled)
                const float y    = gxv + ghv;
                const float sact = RCPF(1.0f + EXP2F(-y));    // sigmoid (r,z)
#ifdef HAS_PLSWAP
                // permlane32_swap(a,a): res0.row2 = a.row0 -> n-lanes get r;
                //                       res1.row0 = a.row2 -> h-lanes get nn.
                // permlane16_swap(a,a): res1.row0 = a.row1 -> h-lanes get z.
                const uint2v pr = __builtin_amdgcn_permlane32_swap(
                    __float_as_uint(sact), __float_as_uint(sact), false, false);
                const float r  = __uint_as_float(pr[0]);      // valid lanes 32..47
                const float nv = tanh_pre(gxv + r * ghv);     // n-lanes
                const uint2v pz = __builtin_amdgcn_permlane16_swap(
                    __float_as_uint(sact), __float_as_uint(sact), false, false);
                const float z  = __uint_as_float(pz[1]);      // valid lanes 0..15
                const uint2v pn = __builtin_amdgcn_permlane32_swap(
                    __float_as_uint(nv), __float_as_uint(nv), false, false);
                const float nn = __uint_as_float(pn[1]);      // valid lanes 0..15
#else
                const float r    = __shfl_xor(sact, 32);      // n-lanes fetch r
                const float nv   = tanh_pre(gxv + r * ghv);   // n-lanes
                const float z    = __shfl_xor(sact, 16);      // h-lanes fetch z
                const float nn   = __shfl_xor(nv, 32);        // h-lanes fetch n
#endif
                const float hnew = nn + z * (h_own - nn);
                h_own = hnew;                                 // valid in lanes<16
                if (lane < HD)
                    hwr[ls * H1ROW] = (_Float16)hnew;         // imm offset, pure sink
            }
            afrag = afrag_n;
        }
    }
    __syncthreads();

    // attention scratch overlays the (now dead) ring
    float* w_sh = reinterpret_cast<float*>(smem_u);            // 512 B
    float* red  = reinterpret_cast<float*>(smem_u + 512);      // 16 B
    float* cvp  = reinterpret_cast<float*>(smem_u + 528);      // 512 B

    // ---- Attention: tanh proj -> softmax over t -> weighted sum ----
    // h1[t][0..15] = fwd (s=t), h1[t][16..31] = bwd (s=127-t)
    {
        const int t = tid;
        float hh[AD];
        {
            const f16x8* fp = reinterpret_cast<const f16x8*>(&h1pool[0][t][0]);
            const f16x8* bp = reinterpret_cast<const f16x8*>(&h1pool[1][TSTEPS - 1 - t][0]);
            const f16x8 f0 = fp[0], f1 = fp[1], b0v = bp[0], b1v = bp[1];
            #pragma unroll
            for (int e = 0; e < 8; ++e) {
                hh[e]      = (float)f0[e];
                hh[8 + e]  = (float)f1[e];
                hh[16 + e] = (float)b0v[e];
                hh[24 + e] = (float)b1v[e];
            }
        }
        float st = 0.0f;
        for (int i = 0; i < AD; ++i) {
            float a0 = ba[i], a1 = 0.f;
            const float* war = &Wa[i * AD];
            #pragma unroll
            for (int k = 0; k < AD; k += 2) {
                a0 += war[k] * hh[k];
                a1 += war[k + 1] * hh[k + 1];
            }
            st += tanh_pre(SC2 * (a0 + a1)) * ctxv[i];
        }
        // softmax across the 128 threads (2 waves)
        float m = st;
        #pragma unroll
        for (int off = 32; off > 0; off >>= 1) m = fmaxf(m, __shfl_xor(m, off));
        if (lane == 0) red[wave] = m;
        __syncthreads();
        m = fmaxf(red[0], red[1]);
        const float e = EXP2F(SC1 * (st - m));
        float ssum = e;
        #pragma unroll
        for (int off = 32; off > 0; off >>= 1) ssum += __shfl_xor(ssum, off);
        if (lane == 0) red[2 + wave] = ssum;
        __syncthreads();
        const float Z = red[2] + red[3];
        w_sh[tid] = e * RCPF(Z);
    }
    __syncthreads();

    // cv[i] = sum_t w[t] * h1[t][i]   (4 partial groups of 32 t's each)
    {
        const int g = tid >> 5, i = tid & 31;
        const _Float16* p;
        int stp;
        if (i < HD) { p = &h1pool[0][g * 32][i];                 stp =  H1ROW; }
        else        { p = &h1pool[1][TSTEPS - 1 - g * 32][i - HD]; stp = -H1ROW; }
        float acc = 0.0f;
        for (int k = 0; k < 32; ++k) {
            acc += w_sh[g * 32 + k] * (float)(*p);
            p += stp;
        }
        cvp[g * AD + i] = acc;
    }
    __syncthreads();
    if (tid < AD)
        cvp[tid] = cvp[tid] + cvp[AD + tid] + cvp[2 * AD + tid] + cvp[3 * AD + tid];
    __syncthreads();

    if (HAS_PROJ) {
        if (tid < 16) {
            float acc = bm[tid];
            #pragma unroll
            for (int i = 0; i < AD; ++i) acc += Wm[tid * AD + i] * cvp[i];
            out[(size_t)seq * out_cols + tid] = acc;
        }
    } else {
        if (tid < AD) out[(size_t)seq * out_cols + tid] = cvp[tid];
    }
}

extern "C" void kernel_launch(void* const* d_in, const int* in_sizes, int n_in,
                              void* d_out, int out_size, void* d_ws, size_t ws_size,
                              hipStream_t stream) {
    const float* x     = (const float*)d_in[0];
    const float* Wih1f = (const float*)d_in[1];
    const float* Whh1f = (const float*)d_in[2];
    const float* bih1f = (const float*)d_in[3];
    const float* bhh1f = (const float*)d_in[4];
    const float* Wih1b = (const float*)d_in[5];
    const float* Whh1b = (const float*)d_in[6];
    const float* bih1b = (const float*)d_in[7];
    const float* bhh1b = (const float*)d_in[8];
    const float* Wih2f = (const float*)d_in[9];
    const float* Whh2f = (const float*)d_in[10];
    const float* bih2f = (const float*)d_in[11];
    const float* bhh2f = (const float*)d_in[12];
    const float* Wih2b = (const float*)d_in[13];
    const float* Whh2b = (const float*)d_in[14];
    const float* bih2b = (const float*)d_in[15];
    const float* bhh2b = (const float*)d_in[16];
    const float* Wa1   = (const float*)d_in[17];
    const float* ba1   = (const float*)d_in[18];
    const float* ctx1  = (const float*)d_in[19];
    const float* Wa2   = (const float*)d_in[20];
    const float* ba2   = (const float*)d_in[21];
    const float* ctx2  = (const float*)d_in[22];
    const float* Wm    = (const float*)d_in[23];
    const float* bm    = (const float*)d_in[24];

    float* flow = (float*)d_ws;          // [8192, 16]
    float* outp = (float*)d_out;         // [64, 32]

    // Stage 1: 8192 sequences (B*N), D=25
    gru_attn_kernel<25, true><<<8192, 128, 0, stream>>>(
        x, Wih1f, Whh1f, bih1f, bhh1f, Wih1b, Whh1b, bih1b, bhh1b,
        Wa1, ba1, ctx1, Wm, bm, flow, 16);

    // Stage 2: 64 sequences (B), input = flow viewed as [64, 128, 16]
    gru_attn_kernel<16, false><<<64, 128, 0, stream>>>(
        flow, Wih2f, Whh2f, bih2f, bhh2f, Wih2b, Whh2b, bih2b, bhh2b,
        Wa2, ba2, ctx2, nullptr, nullptr, outp, 32);
}

// Round 15
// 214.274 us; speedup vs baseline: 1.4132x; 1.0949x over previous
//
#include <hip/hip_runtime.h>
#include <hip/hip_bf16.h>
#include <math.h>

#define TSTEPS 128
#define HD 16      // GRU hidden
#define G3 48      // 3*H gates
#define AD 32      // 2*H attention dim
#define CHUNK 8    // serial steps per gx-MFMA chunk
#define NCHK 16
#define RROW 18    // ring row halfs (16 + 2 pad -> conflict-free group reads)
#define RING_PW (4 * 3 * CHUNK * RROW)   // 1728 halfs per wave
#define H1W 36     // K2 LDS row width in halfs (72B, 8B-aligned, 4-way max)
#define SEQ_HALFS 4096                   // per-seq history: 16c * 32u * 8

#define SC1 1.44269504088896340736f   // log2(e)   : sigmoid prescale
#define SC2 2.88539008177792681472f   // 2*log2(e) : tanh prescale

typedef _Float16 h2 __attribute__((ext_vector_type(2)));
typedef _Float16 h4 __attribute__((ext_vector_type(4)));
typedef _Float16 f16x8 __attribute__((ext_vector_type(8)));
typedef float f32x4 __attribute__((ext_vector_type(4)));

#if defined(__has_builtin)
#  if __has_builtin(__builtin_amdgcn_exp2f)
#    define EXP2F(x) __builtin_amdgcn_exp2f(x)
#  endif
#  if __has_builtin(__builtin_amdgcn_rcpf)
#    define RCPF(x) __builtin_amdgcn_rcpf(x)
#  endif
#endif
#ifndef EXP2F
#  define EXP2F(x) exp2f(x)
#endif
#ifndef RCPF
#  define RCPF(x) (1.0f / (x))
#endif

__device__ __forceinline__ float fdot2(h2 a, h2 b, float c) {
    return __builtin_amdgcn_fdot2(a, b, c, false);
}
// tanh(x) with pre-scaled input u = 2*log2e*x
__device__ __forceinline__ float tanh_pre(float u) {
    return 1.0f - 2.0f * RCPF(EXP2F(u) + 1.0f);
}

// Guarded row-major MFMA fragment load (k = k0+e, 0 beyond D), scaled.
template<int D>
__device__ __forceinline__ f16x8 load_frag(const float* __restrict__ rowptr,
                                           int k0, float scale) {
    f16x8 f;
    #pragma unroll
    for (int e = 0; e < 8; ++e) {
        const int k = k0 + e;
        f[e] = (k < D) ? (_Float16)(rowptr[k] * scale) : (_Float16)0.0f;
    }
    return f;
}

// ---------------- K1: serial recurrence only (dense: 4 seqs/block) ----------
// 128 threads = 2 waves. wave0 = fwd, wave1 = bwd, each over the block's 4
// seqs. Lane (g,u): seq g, h-unit u, computes all three gates (24 fdot2,
// no cross-lane ops). gx = x @ Wih^T via MFMA per 8-step chunk into a
// per-wave LDS ring. h history streamed to global, packed 16B/lane/chunk:
// layout [seq][c(16)][u32(32)][8] halfs; bwd uses chunk 15-c (elements stay
// s-ordered; K2 un-flips with e^7).
template<int D>
__global__ __launch_bounds__(128, 3)
void gru_serial_kernel(
    const float* __restrict__ x,                      // [S, TSTEPS, D]
    const float* __restrict__ Wih_f, const float* __restrict__ Whh_f,
    const float* __restrict__ bih_f, const float* __restrict__ bhh_f,
    const float* __restrict__ Wih_b, const float* __restrict__ Whh_b,
    const float* __restrict__ bih_b, const float* __restrict__ bhh_b,
    _Float16* __restrict__ ghist)
{
    __shared__ __align__(16) _Float16 ring[2 * RING_PW];   // 6912 B
    __shared__ __align__(16) _Float16 hx[8 * HD];          // 256 B exchange rows

    const int tid  = threadIdx.x;
    const int lane = tid & 63;
    const int wv   = tid >> 6;
    const int dir  = wv;                 // wave0 = fwd, wave1 = bwd
    const int g    = lane >> 4;          // seq index within block (0..3)
    const int u    = lane & 15;          // h-unit / fragment row/col
    const int k0   = g * 8;              // fragment k base
    const int sd   = wv * 4 + g;

    const float* WihP = dir ? Wih_b : Wih_f;
    const float* WhhP = dir ? Whh_b : Whh_f;
    const float* bihP = dir ? bih_b : bih_f;
    const float* bhhP = dir ? bhh_b : bhh_f;

    // per-lane recurrent weights (prescaled) + biases
    h2 wr_[8], wz_[8], wn_[8];
    {
        const float4* wrp = (const float4*)(WhhP + u * HD);
        const float4* wzp = (const float4*)(WhhP + (HD + u) * HD);
        const float4* wnp = (const float4*)(WhhP + (2 * HD + u) * HD);
        #pragma unroll
        for (int p = 0; p < 4; ++p) {
            const float4 a = wrp[p], b = wzp[p], cn = wnp[p];
            wr_[2*p]   = (h2){(_Float16)(a.x * SC1), (_Float16)(a.y * SC1)};
            wr_[2*p+1] = (h2){(_Float16)(a.z * SC1), (_Float16)(a.w * SC1)};
            wz_[2*p]   = (h2){(_Float16)(b.x * SC1), (_Float16)(b.y * SC1)};
            wz_[2*p+1] = (h2){(_Float16)(b.z * SC1), (_Float16)(b.w * SC1)};
            wn_[2*p]   = (h2){(_Float16)(cn.x * SC2), (_Float16)(cn.y * SC2)};
            wn_[2*p+1] = (h2){(_Float16)(cn.z * SC2), (_Float16)(cn.w * SC2)};
        }
    }
    const float brz = (bihP[u] + bhhP[u]) * SC1;
    const float bzz = (bihP[HD + u] + bhhP[HD + u]) * SC1;
    const float bxn = bihP[2 * HD + u] * SC2;
    const float bhn = bhhP[2 * HD + u] * SC2;

    // persistent B fragments: this wave's dir only
    f16x8 bfrag[3];
    #pragma unroll
    for (int n = 0; n < 3; ++n)
        bfrag[n] = load_frag<D>(WihP + (16 * n + u) * D, k0, n < 2 ? SC1 : SC2);

    // A-fragment sources: tile A = seqs {0,1}, tile B = seqs {2,3}
    const size_t xstride = (size_t)TSTEPS * D;
    const float* xA0 = x + (size_t)(blockIdx.x * 4 + (u >> 3)) * xstride;
    const float* xB0 = xA0 + 2 * xstride;
    const int lsA = u & 7;

    _Float16* ringw = ring + wv * RING_PW;
    const _Float16* ringrd = ringw + (g * 3 * CHUNK) * RROW + u;
    const int lsb0  = ((lane >> 4) & 3) * 4;
    const int wseqA = lsb0 >> 3;
    const int wseqB = 2 + wseqA;
    const int wlsb  = lsb0 & 7;

    // global history: [seq][c][u32][8]; bwd writes chunks in reverse order
    _Float16* ghp = ghist + (size_t)(blockIdx.x * 4 + g) * SEQ_HALFS
                    + (size_t)(dir ? (16 + u) : u) * 8
                    + (dir ? 15 * 256 : 0);
    const int cstep = dir ? -256 : 256;

    _Float16* hxw = hx + sd * HD + u;
    const _Float16* hxr = hx + sd * HD;

    float h_own = 0.0f;

    f16x8 afA = load_frag<D>(xA0 + (size_t)(dir ? (TSTEPS - 1 - lsA) : lsA) * D, k0, 1.0f);
    f16x8 afB = load_frag<D>(xB0 + (size_t)(dir ? (TSTEPS - 1 - lsA) : lsA) * D, k0, 1.0f);

    for (int c = 0; c < NCHK; ++c) {
        // gx via MFMA -> ring
        #pragma unroll
        for (int n = 0; n < 3; ++n) {
            f32x4 a0 = {0.f, 0.f, 0.f, 0.f};
            a0 = __builtin_amdgcn_mfma_f32_16x16x32_f16(afA, bfrag[n], a0, 0, 0, 0);
            #pragma unroll
            for (int q = 0; q < 4; ++q)
                ringw[((wseqA * 3 + n) * CHUNK + wlsb + q) * RROW + u] = (_Float16)a0[q];
            f32x4 a1 = {0.f, 0.f, 0.f, 0.f};
            a1 = __builtin_amdgcn_mfma_f32_16x16x32_f16(afB, bfrag[n], a1, 0, 0, 0);
            #pragma unroll
            for (int q = 0; q < 4; ++q)
                ringw[((wseqB * 3 + n) * CHUNK + wlsb + q) * RROW + u] = (_Float16)a1[q];
        }
        // prefetch next chunk's A fragments
        f16x8 afAn, afBn;
        if (c + 1 < NCHK) {
            const int s0 = (c + 1) * CHUNK + lsA;
            const size_t t0 = (size_t)(dir ? (TSTEPS - 1 - s0) : s0) * D;
            afAn = load_frag<D>(xA0 + t0, k0, 1.0f);
            afBn = load_frag<D>(xB0 + t0, k0, 1.0f);
        }

        f16x8 hpk;

        // serial 8 steps: all 64 lanes active, 3 gates per lane, no shuffles
        #pragma unroll
        for (int ls = 0; ls < CHUNK; ++ls) {
            const float gxr = (float)ringrd[(0 * CHUNK + ls) * RROW];
            const float gxz = (float)ringrd[(1 * CHUNK + ls) * RROW];
            const float gxn = (float)ringrd[(2 * CHUNK + ls) * RROW] + bxn;

            float sr = brz, sr1 = 0.f, sz = bzz, sz1 = 0.f, sn = bhn, sn1 = 0.f;
            if (!(c == 0 && ls == 0)) {
                const f16x8* hp = (const f16x8*)hxr;
                const f16x8 hA = hp[0], hB = hp[1];
                sr  = fdot2(wr_[0], (h2){hA[0], hA[1]}, sr );
                sr1 = fdot2(wr_[1], (h2){hA[2], hA[3]}, sr1);
                sr  = fdot2(wr_[2], (h2){hA[4], hA[5]}, sr );
                sr1 = fdot2(wr_[3], (h2){hA[6], hA[7]}, sr1);
                sr  = fdot2(wr_[4], (h2){hB[0], hB[1]}, sr );
                sr1 = fdot2(wr_[5], (h2){hB[2], hB[3]}, sr1);
                sr  = fdot2(wr_[6], (h2){hB[4], hB[5]}, sr );
                sr1 = fdot2(wr_[7], (h2){hB[6], hB[7]}, sr1);
                sz  = fdot2(wz_[0], (h2){hA[0], hA[1]}, sz );
                sz1 = fdot2(wz_[1], (h2){hA[2], hA[3]}, sz1);
                sz  = fdot2(wz_[2], (h2){hA[4], hA[5]}, sz );
                sz1 = fdot2(wz_[3], (h2){hA[6], hA[7]}, sz1);
                sz  = fdot2(wz_[4], (h2){hB[0], hB[1]}, sz );
                sz1 = fdot2(wz_[5], (h2){hB[2], hB[3]}, sz1);
                sz  = fdot2(wz_[6], (h2){hB[4], hB[5]}, sz );
                sz1 = fdot2(wz_[7], (h2){hB[6], hB[7]}, sz1);
                sn  = fdot2(wn_[0], (h2){hA[0], hA[1]}, sn );
                sn1 = fdot2(wn_[1], (h2){hA[2], hA[3]}, sn1);
                sn  = fdot2(wn_[2], (h2){hA[4], hA[5]}, sn );
                sn1 = fdot2(wn_[3], (h2){hA[6], hA[7]}, sn1);
                sn  = fdot2(wn_[4], (h2){hB[0], hB[1]}, sn );
                sn1 = fdot2(wn_[5], (h2){hB[2], hB[3]}, sn1);
                sn  = fdot2(wn_[6], (h2){hB[4], hB[5]}, sn );
                sn1 = fdot2(wn_[7], (h2){hB[6], hB[7]}, sn1);
            }
            const float ghr = sr + sr1;
            const float ghz = sz + sz1;
            const float ghn = sn + sn1;

            const float r  = RCPF(1.0f + EXP2F(-(gxr + ghr)));
            const float zz = RCPF(1.0f + EXP2F(-(gxz + ghz)));
            const float nv = tanh_pre(gxn + r * ghn);
            const float hnew = nv + zz * (h_own - nv);
            h_own = hnew;
            const _Float16 hh16 = (_Float16)hnew;
            hxw[0] = hh16;               // exchange row (read next step)
            hpk[ls] = hh16;
        }
        *reinterpret_cast<f16x8*>(ghp + c * cstep) = hpk;   // coalesced 16B/lane
        afA = afAn;
        afB = afBn;
    }
}

// ---------------- K2: attention over the streamed history ------------------
// One block = one sequence. Stages 8KB history coalesced into [t][36] LDS
// (bwd elements un-flipped via e^7), then tanh-proj -> softmax -> cv -> proj.
template<bool HAS_PROJ>
__global__ __launch_bounds__(128, 4)
void attn_kernel(
    const _Float16* __restrict__ ghist,
    const float* __restrict__ Wa, const float* __restrict__ ba,
    const float* __restrict__ ctxv,
    const float* __restrict__ Wm, const float* __restrict__ bm,
    float* __restrict__ out, int out_cols)
{
    __shared__ __align__(16) _Float16 h1[TSTEPS * H1W];   // 9216 B
    __shared__ float w_sh[TSTEPS];
    __shared__ float red[4];
    __shared__ float cvp[4 * AD];

    const int tid  = threadIdx.x;
    const int lane = tid & 63;
    const int wave = tid >> 6;
    const int seq  = blockIdx.x;

    // stage ghist[seq] -> h1[t][u32]  (coalesced f16x8 loads)
    {
        const f16x8* src = reinterpret_cast<const f16x8*>(ghist + (size_t)seq * SEQ_HALFS);
        #pragma unroll
        for (int k = 0; k < 4; ++k) {
            const int idx = tid + k * 128;
            const f16x8 v = src[idx];
            const int u32 = idx & 31;            // (idx*8 & 255) >> 3
            const int tb  = (idx >> 5) * 8;      // chunk base t
            const int flip = (u32 >= 16) ? 7 : 0;   // bwd chunks are s-ordered
            #pragma unroll
            for (int e = 0; e < 8; ++e)
                h1[(tb + (e ^ flip)) * H1W + u32] = v[e];
        }
    }
    __syncthreads();

    // tanh proj -> softmax over t
    {
        const int t = tid;
        float hh[AD];
        const h4* hr = reinterpret_cast<const h4*>(&h1[t * H1W]);
        #pragma unroll
        for (int p = 0; p < AD / 4; ++p) {
            const h4 v = hr[p];
            #pragma unroll
            for (int e = 0; e < 4; ++e) hh[4 * p + e] = (float)v[e];
        }
        float st = 0.0f;
        for (int i = 0; i < AD; ++i) {
            float a0 = ba[i], a1 = 0.f;
            const float* war = &Wa[i * AD];
            #pragma unroll
            for (int k = 0; k < AD; k += 2) {
                a0 += war[k] * hh[k];
                a1 += war[k + 1] * hh[k + 1];
            }
            st += tanh_pre(SC2 * (a0 + a1)) * ctxv[i];
        }
        float m = st;
        #pragma unroll
        for (int off = 32; off > 0; off >>= 1) m = fmaxf(m, __shfl_xor(m, off));
        if (lane == 0) red[wave] = m;
        __syncthreads();
        m = fmaxf(red[0], red[1]);
        const float e = EXP2F(SC1 * (st - m));
        float ssum = e;
        #pragma unroll
        for (int off = 32; off > 0; off >>= 1) ssum += __shfl_xor(ssum, off);
        if (lane == 0) red[2 + wave] = ssum;
        __syncthreads();
        const float Z = red[2] + red[3];
        w_sh[tid] = e * RCPF(Z);
    }
    __syncthreads();

    // cv[i] = sum_t w[t] * h1[t][i]
    {
        const int g = tid >> 5, i = tid & 31;
        float acc = 0.0f;
        for (int k = 0; k < 32; ++k) {
            const int tt = g * 32 + k;
            acc += w_sh[tt] * (float)h1[tt * H1W + i];
        }
        cvp[g * AD + i] = acc;
    }
    __syncthreads();
    if (tid < AD)
        cvp[tid] = cvp[tid] + cvp[AD + tid] + cvp[2 * AD + tid] + cvp[3 * AD + tid];
    __syncthreads();

    if (HAS_PROJ) {
        if (tid < HD) {
            float acc = bm[tid];
            #pragma unroll
            for (int i = 0; i < AD; ++i) acc += Wm[tid * AD + i] * cvp[i];
            out[(size_t)seq * out_cols + tid] = acc;
        }
    } else {
        if (tid < AD) out[(size_t)seq * out_cols + tid] = cvp[tid];
    }
}

extern "C" void kernel_launch(void* const* d_in, const int* in_sizes, int n_in,
                              void* d_out, int out_size, void* d_ws, size_t ws_size,
                              hipStream_t stream) {
    const float* x     = (const float*)d_in[0];
    const float* Wih1f = (const float*)d_in[1];
    const float* Whh1f = (const float*)d_in[2];
    const float* bih1f = (const float*)d_in[3];
    const float* bhh1f = (const float*)d_in[4];
    const float* Wih1b = (const float*)d_in[5];
    const float* Whh1b = (const float*)d_in[6];
    const float* bih1b = (const float*)d_in[7];
    const float* bhh1b = (const float*)d_in[8];
    const float* Wih2f = (const float*)d_in[9];
    const float* Whh2f = (const float*)d_in[10];
    const float* bih2f = (const float*)d_in[11];
    const float* bhh2f = (const float*)d_in[12];
    const float* Wih2b = (const float*)d_in[13];
    const float* Whh2b = (const float*)d_in[14];
    const float* bih2b = (const float*)d_in[15];
    const float* bhh2b = (const float*)d_in[16];
    const float* Wa1   = (const float*)d_in[17];
    const float* ba1   = (const float*)d_in[18];
    const float* ctx1  = (const float*)d_in[19];
    const float* Wa2   = (const float*)d_in[20];
    const float* ba2   = (const float*)d_in[21];
    const float* ctx2  = (const float*)d_in[22];
    const float* Wm    = (const float*)d_in[23];
    const float* bm    = (const float*)d_in[24];

    float* flow = (float*)d_ws;                               // [8192,16] = 512KB
    const size_t histOff = 1u << 20;                          // 1 MB
    _Float16* ghist = (_Float16*)((char*)d_ws + histOff);     // 64 MB (reused by s2)
    float* outp = (float*)d_out;                              // [64, 32]

    // Stage 1: 8192 seqs, 4 per block -> history; then attention -> flow
    gru_serial_kernel<25><<<2048, 128, 0, stream>>>(
        x, Wih1f, Whh1f, bih1f, bhh1f, Wih1b, Whh1b, bih1b, bhh1b, ghist);
    attn_kernel<true><<<8192, 128, 0, stream>>>(
        ghist, Wa1, ba1, ctx1, Wm, bm, flow, 16);

    // Stage 2: 64 seqs (input = flow as [64,128,16]); ghist buffer reused
    gru_serial_kernel<16><<<16, 128, 0, stream>>>(
        flow, Wih2f, Whh2f, bih2f, bhh2f, Wih2b, Whh2b, bih2b, bhh2b, ghist);
    attn_kernel<false><<<64, 128, 0, stream>>>(
        ghist, Wa2, ba2, ctx2, nullptr, nullptr, outp, 32);
}